// Round 1
// baseline (1174.812 us; speedup 1.0000x reference)
//
#include <hip/hip_runtime.h>

typedef unsigned short u16;
typedef __bf16 bf16_t;
typedef bf16_t bf16x8 __attribute__((ext_vector_type(8)));
typedef float f32x4 __attribute__((ext_vector_type(4)));

#define B_ 2
#define S_ 2048
#define DIM_ 4096
#define NH_ 32
#define NKV_ 8
#define HD_ 128

__device__ __forceinline__ u16 f2b(float f) {
  union { float f; unsigned u; } x; x.f = f;
  unsigned r = x.u + 0x7fffu + ((x.u >> 16) & 1u);
  return (u16)(r >> 16);
}
__device__ __forceinline__ float b2f(u16 u) {
  union { unsigned u; float f; } x; x.u = ((unsigned)u) << 16;
  return x.f;
}

#define GLDS(gsrc, ldst) \
  __builtin_amdgcn_global_load_lds((const __attribute__((address_space(1))) void*)(gsrc), \
                                   (__attribute__((address_space(3))) void*)(ldst), 16, 0, 0)

// ---------------- f32 -> bf16 conversion ----------------
__global__ void cvt_kernel(const float* __restrict__ in, u16* __restrict__ out, int n4) {
  int i = blockIdx.x * blockDim.x + threadIdx.x;
  int stride = gridDim.x * blockDim.x;
  for (; i < n4; i += stride) {
    float4 v = ((const float4*)in)[i];
    ushort4 o;
    o.x = f2b(v.x); o.y = f2b(v.y); o.z = f2b(v.z); o.w = f2b(v.w);
    ((ushort4*)out)[i] = o;
  }
}

// ---------------- RoPE (in-place on bf16) ----------------
__global__ void rope_kernel(u16* __restrict__ t, const float* __restrict__ fc,
                            const float* __restrict__ fs, int nheads) {
  int idx = blockIdx.x * blockDim.x + threadIdx.x;  // one interleaved pair per thread
  int ppr = nheads * 64;                            // pairs per row
  int row = idx / ppr;                              // 0 .. B*S-1
  int pr = idx - row * ppr;
  int h = pr >> 6, j = pr & 63;
  int s = row & (S_ - 1);
  float c = fc[s * 64 + j], sn = fs[s * 64 + j];
  u16* p = t + (size_t)row * (size_t)(nheads * HD_) + h * HD_ + j * 2;
  float tr = b2f(p[0]), ti = b2f(p[1]);
  p[0] = f2b(tr * c - ti * sn);
  p[1] = f2b(tr * sn + ti * c);
}

// ---------------- GEMM: C[M,N] = A[M,K] * B[N,K]^T  (bf16 in, bf16/f32 out) ----------------
// m97 structure: 128x128 tile, BK=32, 4 waves (2x2), 4x4 16x16 frags per wave,
// global_load_lds width 16, linear LDS.
template<int F32OUT>
__global__ __launch_bounds__(256) void gemm_bt(const u16* __restrict__ A,
                                               const u16* __restrict__ B,
                                               void* __restrict__ Cout,
                                               int M, int N, int K) {
  __shared__ u16 As[128 * 32];
  __shared__ u16 Bs[128 * 32];
  const int nbn = N >> 7;
  const int bm = blockIdx.x / nbn;
  const int bn = blockIdx.x - bm * nbn;
  const int tid = threadIdx.x;
  const int lane = tid & 63;
  const int wv = tid >> 6;
  const int wr = wv >> 1, wc = wv & 1;

  f32x4 acc[4][4];
#pragma unroll
  for (int i = 0; i < 4; i++)
#pragma unroll
    for (int j = 0; j < 4; j++)
#pragma unroll
      for (int r = 0; r < 4; r++) acc[i][j][r] = 0.0f;

  const int srow = tid >> 2;          // staging row within 64-row half
  const int scol = (tid & 3) * 8;     // staging col (elems)
  const u16* Abase = A + (size_t)(bm * 128 + srow) * K + scol;
  const u16* Bbase = B + (size_t)(bn * 128 + srow) * K + scol;

  const int koffr = (lane >> 4) * 8;
  const int mrow = lane & 15;

  for (int k0 = 0; k0 < K; k0 += 32) {
    __syncthreads();
    GLDS(Abase + k0,                    &As[wv * 512]);
    GLDS(Abase + (size_t)64 * K + k0,   &As[(4 + wv) * 512]);
    GLDS(Bbase + k0,                    &Bs[wv * 512]);
    GLDS(Bbase + (size_t)64 * K + k0,   &Bs[(4 + wv) * 512]);
    __syncthreads();
    bf16x8 af[4], bfr[4];
#pragma unroll
    for (int i = 0; i < 4; i++)
      af[i] = *(const bf16x8*)&As[(wr * 64 + i * 16 + mrow) * 32 + koffr];
#pragma unroll
    for (int j = 0; j < 4; j++)
      bfr[j] = *(const bf16x8*)&Bs[(wc * 64 + j * 16 + mrow) * 32 + koffr];
#pragma unroll
    for (int i = 0; i < 4; i++)
#pragma unroll
      for (int j = 0; j < 4; j++)
        acc[i][j] = __builtin_amdgcn_mfma_f32_16x16x32_bf16(af[i], bfr[j], acc[i][j], 0, 0, 0);
  }

  // C/D layout: col = lane&15, row = (lane>>4)*4 + reg
  const int r0 = bm * 128 + wr * 64 + (lane >> 4) * 4;
  const int c0 = bn * 128 + wc * 64 + (lane & 15);
#pragma unroll
  for (int i = 0; i < 4; i++)
#pragma unroll
    for (int j = 0; j < 4; j++)
#pragma unroll
      for (int r = 0; r < 4; r++) {
        size_t off = (size_t)(r0 + i * 16 + r) * N + (c0 + j * 16);
        if (F32OUT) ((float*)Cout)[off] = acc[i][j][r];
        else        ((u16*)Cout)[off]  = f2b(acc[i][j][r]);
      }
}

// ---------------- Flash attention (causal, GQA 4:1) ----------------
// 1 block = 64 q rows of one (b,h); 4 waves x 16 q rows. KV tiles of 32 staged in LDS.
__global__ __launch_bounds__(256) void attn_kernel(const u16* __restrict__ Q,
                                                   const u16* __restrict__ Kt,
                                                   const u16* __restrict__ Vt,
                                                   u16* __restrict__ O) {
  __shared__ u16 Ks[32 * 128];   // XOR-swizzled rows
  __shared__ u16 Vs[32 * 128];   // linear
  __shared__ u16 Ps[4][16 * 32]; // per-wave P transpose bounce

  const int bid = blockIdx.x;
  const int qb = bid & 31;
  const int h = (bid >> 5) & 31;
  const int b = bid >> 10;
  const int g = h >> 2;          // kv head
  const int tid = threadIdx.x;
  const int lane = tid & 63;
  const int wv = tid >> 6;
  const int qrow0 = qb * 64 + wv * 16;
  const float scale = 0.08838834764831845f;  // 1/sqrt(128)

  // Q fragments: A-frag row = lane&15, k = (lane>>4)*8+j, 4 chunks of K=32 over d=128
  bf16x8 qf[4];
  {
    const int qr = qrow0 + (lane & 15);
    const u16* qptr = Q + (size_t)(b * S_ + qr) * (NH_ * HD_) + h * HD_ + (lane >> 4) * 8;
#pragma unroll
    for (int c = 0; c < 4; c++) qf[c] = *(const bf16x8*)(qptr + c * 32);
  }

  float m[4], l[4];
  f32x4 o[8];
#pragma unroll
  for (int r = 0; r < 4; r++) { m[r] = -1e30f; l[r] = 0.f; }
#pragma unroll
  for (int c = 0; c < 8; c++)
#pragma unroll
    for (int r = 0; r < 4; r++) o[c][r] = 0.f;

  const int skey = tid >> 4;          // staging row (key) 0..15 (+16 pass 1)
  const int scolb = (tid & 15) * 16;  // staging byte col within 256B row
  const int nkv = 2 * qb + 2;
  const size_t kvrow0 = (size_t)b * S_;

  for (int t = 0; t < nkv; t++) {
    __syncthreads();
#pragma unroll
    for (int p = 0; p < 2; p++) {
      int key = p * 16 + skey;
      int gk = t * 32 + key;
      // K: pre-swizzled global source -> linear LDS dest == swizzled layout
      int srcbK = scolb ^ ((key & 7) << 4);
      const u16* ksrc = Kt + (kvrow0 + gk) * (NKV_ * HD_) + g * HD_ + (srcbK >> 1);
      GLDS(ksrc, &Ks[(p * 4 + wv) * 512]);
      const u16* vsrc = Vt + (kvrow0 + gk) * (NKV_ * HD_) + g * HD_ + (scolb >> 1);
      GLDS(vsrc, &Vs[(p * 4 + wv) * 512]);
    }
    __syncthreads();

    if (t * 32 <= qrow0 + 15) {
      // ---- QK^T: 2 n-frags (32 keys), 4 k-chunks each ----
      f32x4 s[2];
#pragma unroll
      for (int n = 0; n < 2; n++) {
        f32x4 sc;
#pragma unroll
        for (int r = 0; r < 4; r++) sc[r] = 0.f;
        int kcol = n * 16 + (lane & 15);
#pragma unroll
        for (int c = 0; c < 4; c++) {
          int colb = c * 64 + ((lane >> 4) * 16);
          int addr = kcol * 256 + (colb ^ ((kcol & 7) << 4));
          bf16x8 kf = *(const bf16x8*)((const char*)Ks + addr);
          sc = __builtin_amdgcn_mfma_f32_16x16x32_bf16(qf[c], kf, sc, 0, 0, 0);
        }
        s[n] = sc;
      }
      // ---- causal mask (raw scores; scale folded into exp) ----
      if (t * 32 + 31 > qrow0) {
#pragma unroll
        for (int n = 0; n < 2; n++) {
          int k = t * 32 + n * 16 + (lane & 15);
#pragma unroll
          for (int r = 0; r < 4; r++) {
            int q = qrow0 + (lane >> 4) * 4 + r;
            if (k > q) s[n][r] = -1e9f;
          }
        }
      }
      // ---- online softmax ----
      float mx[4];
#pragma unroll
      for (int r = 0; r < 4; r++) mx[r] = fmaxf(s[0][r], s[1][r]);
#pragma unroll
      for (int off = 1; off < 16; off <<= 1)
#pragma unroll
        for (int r = 0; r < 4; r++) mx[r] = fmaxf(mx[r], __shfl_xor(mx[r], off));
      float alpha[4], mn[4];
#pragma unroll
      for (int r = 0; r < 4; r++) {
        mn[r] = fmaxf(m[r], mx[r]);
        alpha[r] = __expf(scale * (m[r] - mn[r]));
        m[r] = mn[r];
      }
      float rs[4];
#pragma unroll
      for (int r = 0; r < 4; r++) {
        s[0][r] = __expf(scale * (s[0][r] - mn[r]));
        s[1][r] = __expf(scale * (s[1][r] - mn[r]));
        rs[r] = s[0][r] + s[1][r];
      }
#pragma unroll
      for (int off = 1; off < 16; off <<= 1)
#pragma unroll
        for (int r = 0; r < 4; r++) rs[r] += __shfl_xor(rs[r], off);
#pragma unroll
      for (int r = 0; r < 4; r++) l[r] = l[r] * alpha[r] + rs[r];
#pragma unroll
      for (int c = 0; c < 8; c++)
#pragma unroll
        for (int r = 0; r < 4; r++) o[c][r] *= alpha[r];
      // ---- P (D layout) -> LDS -> A-frag layout ----
#pragma unroll
      for (int n = 0; n < 2; n++)
#pragma unroll
        for (int r = 0; r < 4; r++)
          Ps[wv][((lane >> 4) * 4 + r) * 32 + n * 16 + (lane & 15)] = f2b(s[n][r]);
      asm volatile("s_waitcnt lgkmcnt(0)" ::: "memory");
      bf16x8 pa = *(const bf16x8*)&Ps[wv][(lane & 15) * 32 + (lane >> 4) * 8];
      // ---- PV: 8 d-chunks; B-frag from Vs via scalar reads (round-1 simple) ----
#pragma unroll
      for (int c = 0; c < 8; c++) {
        union { bf16x8 v; u16 u[8]; } vf;
        int d = c * 16 + (lane & 15);
#pragma unroll
        for (int j = 0; j < 8; j++) {
          int key = (lane >> 4) * 8 + j;
          vf.u[j] = Vs[key * 128 + d];
        }
        o[c] = __builtin_amdgcn_mfma_f32_16x16x32_bf16(pa, vf.v, o[c], 0, 0, 0);
      }
    }
  }

  // ---- epilogue: normalize, write bf16 ----
#pragma unroll
  for (int c = 0; c < 8; c++)
#pragma unroll
    for (int r = 0; r < 4; r++) {
      int q = qrow0 + (lane >> 4) * 4 + r;
      float val = o[c][r] / l[r];
      O[(size_t)(b * S_ + q) * (NH_ * HD_) + h * HD_ + c * 16 + (lane & 15)] = f2b(val);
    }
}

// ---------------- launch ----------------
extern "C" void kernel_launch(void* const* d_in, const int* in_sizes, int n_in,
                              void* d_out, int out_size, void* d_ws, size_t ws_size,
                              hipStream_t stream) {
  const float* x  = (const float*)d_in[0];
  const float* wq = (const float*)d_in[1];
  const float* wk = (const float*)d_in[2];
  const float* wv = (const float*)d_in[3];
  const float* wo = (const float*)d_in[4];
  const float* fc = (const float*)d_in[5];
  const float* fs = (const float*)d_in[6];
  // d_in[7] = mask (causal, computed inline), d_in[8] = start_pos (0)

  char* ws = (char*)d_ws;
  // 128 MB total with reuse
  u16* Xb  = (u16*)(ws);                 // 33.5 MB   (later reused as Ow)
  u16* Wqb = (u16*)(ws + 33554432);      // 33.5 MB   (later reused as Wob)
  u16* Wkb = (u16*)(ws + 67108864);      // 8.4 MB
  u16* Wvb = (u16*)(ws + 75497472);      // 8.4 MB
  u16* Qw  = (u16*)(ws + 83886080);      // 33.5 MB
  u16* Kw  = (u16*)(ws + 117440512);     // 8.4 MB
  u16* Vw  = (u16*)(ws + 125829120);     // 8.4 MB
  u16* Ow  = Xb;
  u16* Wob = Wqb;

  auto cvt = [&](const float* in, u16* out, int n) {
    int n4 = n >> 2;
    int blocks = (n4 + 255) / 256; if (blocks > 2048) blocks = 2048;
    cvt_kernel<<<dim3(blocks), dim3(256), 0, stream>>>(in, out, n4);
  };
  cvt(x,  Xb,  B_ * S_ * DIM_);
  cvt(wq, Wqb, DIM_ * DIM_);
  cvt(wk, Wkb, NKV_ * HD_ * DIM_);
  cvt(wv, Wvb, NKV_ * HD_ * DIM_);

  gemm_bt<0><<<dim3(32 * 32), 256, 0, stream>>>(Xb, Wqb, Qw, 4096, 4096, 4096);
  gemm_bt<0><<<dim3(32 * 8),  256, 0, stream>>>(Xb, Wkb, Kw, 4096, 1024, 4096);
  gemm_bt<0><<<dim3(32 * 8),  256, 0, stream>>>(Xb, Wvb, Vw, 4096, 1024, 4096);

  // wo conversion into Wqb's slot (free after Q GEMM; stream-ordered)
  cvt(wo, Wob, DIM_ * DIM_);

  rope_kernel<<<dim3((B_ * S_ * NH_ * 64) / 256), 256, 0, stream>>>(Qw, fc, fs, NH_);
  rope_kernel<<<dim3((B_ * S_ * NKV_ * 64) / 256), 256, 0, stream>>>(Kw, fc, fs, NKV_);

  attn_kernel<<<dim3(B_ * NH_ * (S_ / 64)), 256, 0, stream>>>(Qw, Kw, Vw, Ow);

  gemm_bt<1><<<dim3(32 * 32), 256, 0, stream>>>(Ow, Wob, d_out, 4096, 4096, 4096);
}

// Round 2
// 846.681 us; speedup vs baseline: 1.3876x; 1.3876x over previous
//
#include <hip/hip_runtime.h>

typedef unsigned short u16;
typedef __bf16 bf16_t;
typedef bf16_t bf16x8 __attribute__((ext_vector_type(8)));
typedef float f32x4 __attribute__((ext_vector_type(4)));

#define B_ 2
#define S_ 2048
#define DIM_ 4096
#define NH_ 32
#define NKV_ 8
#define HD_ 128

__device__ __forceinline__ u16 f2b(float f) {
  union { float f; unsigned u; } x; x.f = f;
  unsigned r = x.u + 0x7fffu + ((x.u >> 16) & 1u);
  return (u16)(r >> 16);
}
__device__ __forceinline__ float b2f(u16 u) {
  union { unsigned u; float f; } x; x.u = ((unsigned)u) << 16;
  return x.f;
}

#define GLDS(gsrc, ldst) \
  __builtin_amdgcn_global_load_lds((const __attribute__((address_space(1))) void*)(gsrc), \
                                   (__attribute__((address_space(3))) void*)(ldst), 16, 0, 0)
#define BAR()    __builtin_amdgcn_s_barrier()
#define SCHED0() __builtin_amdgcn_sched_barrier(0)

// ---------------- f32 -> bf16 conversion ----------------
__global__ void cvt_kernel(const float* __restrict__ in, u16* __restrict__ out, int n4) {
  int i = blockIdx.x * blockDim.x + threadIdx.x;
  int stride = gridDim.x * blockDim.x;
  for (; i < n4; i += stride) {
    float4 v = ((const float4*)in)[i];
    ushort4 o;
    o.x = f2b(v.x); o.y = f2b(v.y); o.z = f2b(v.z); o.w = f2b(v.w);
    ((ushort4*)out)[i] = o;
  }
}

// ---------------- RoPE (in-place on bf16) ----------------
__global__ void rope_kernel(u16* __restrict__ t, const float* __restrict__ fc,
                            const float* __restrict__ fs, int nheads) {
  int idx = blockIdx.x * blockDim.x + threadIdx.x;
  int ppr = nheads * 64;
  int row = idx / ppr;
  int pr = idx - row * ppr;
  int h = pr >> 6, j = pr & 63;
  int s = row & (S_ - 1);
  float c = fc[s * 64 + j], sn = fs[s * 64 + j];
  u16* p = t + (size_t)row * (size_t)(nheads * HD_) + h * HD_ + j * 2;
  float tr = b2f(p[0]), ti = b2f(p[1]);
  p[0] = f2b(tr * c - ti * sn);
  p[1] = f2b(tr * sn + ti * c);
}

// ---------------- GEMM: C = A[M,K] * B[N,K]^T ----------------
// MODE 0: bf16 row-major [M][N]; MODE 1: f32 row-major; MODE 2: bf16 col-major [N][M] (C^T)
template<int MODE>
__global__ __launch_bounds__(256) void gemm_bt(const u16* __restrict__ A,
                                               const u16* __restrict__ B,
                                               void* __restrict__ Cout,
                                               int M, int N, int K) {
  __shared__ u16 As[128 * 32];
  __shared__ u16 Bs[128 * 32];
  const int nbn = N >> 7;
  const int bm = blockIdx.x / nbn;
  const int bn = blockIdx.x - bm * nbn;
  const int tid = threadIdx.x;
  const int lane = tid & 63;
  const int wv = tid >> 6;
  const int wr = wv >> 1, wc = wv & 1;

  f32x4 acc[4][4];
#pragma unroll
  for (int i = 0; i < 4; i++)
#pragma unroll
    for (int j = 0; j < 4; j++)
#pragma unroll
      for (int r = 0; r < 4; r++) acc[i][j][r] = 0.0f;

  const int srow = tid >> 2;
  const int scol = (tid & 3) * 8;
  const u16* Abase = A + (size_t)(bm * 128 + srow) * K + scol;
  const u16* Bbase = B + (size_t)(bn * 128 + srow) * K + scol;

  const int koffr = (lane >> 4) * 8;
  const int mrow = lane & 15;

  for (int k0 = 0; k0 < K; k0 += 32) {
    __syncthreads();
    GLDS(Abase + k0,                    &As[wv * 512]);
    GLDS(Abase + (size_t)64 * K + k0,   &As[(4 + wv) * 512]);
    GLDS(Bbase + k0,                    &Bs[wv * 512]);
    GLDS(Bbase + (size_t)64 * K + k0,   &Bs[(4 + wv) * 512]);
    __syncthreads();
    bf16x8 af[4], bfr[4];
#pragma unroll
    for (int i = 0; i < 4; i++)
      af[i] = *(const bf16x8*)&As[(wr * 64 + i * 16 + mrow) * 32 + koffr];
#pragma unroll
    for (int j = 0; j < 4; j++)
      bfr[j] = *(const bf16x8*)&Bs[(wc * 64 + j * 16 + mrow) * 32 + koffr];
#pragma unroll
    for (int i = 0; i < 4; i++)
#pragma unroll
      for (int j = 0; j < 4; j++)
        acc[i][j] = __builtin_amdgcn_mfma_f32_16x16x32_bf16(af[i], bfr[j], acc[i][j], 0, 0, 0);
  }

  const int r0 = bm * 128 + wr * 64 + (lane >> 4) * 4;
  const int c0 = bn * 128 + wc * 64 + (lane & 15);
#pragma unroll
  for (int i = 0; i < 4; i++)
#pragma unroll
    for (int j = 0; j < 4; j++)
#pragma unroll
      for (int r = 0; r < 4; r++) {
        int row = r0 + i * 16 + r;
        int col = c0 + j * 16;
        if (MODE == 1)      ((float*)Cout)[(size_t)row * N + col] = acc[i][j][r];
        else if (MODE == 0) ((u16*)Cout)[(size_t)row * N + col]  = f2b(acc[i][j][r]);
        else                ((u16*)Cout)[(size_t)col * M + row]  = f2b(acc[i][j][r]);
      }
}

// ---------------- Flash attention (causal, GQA 4:1) ----------------
// 1 block = 64 q rows of one (b,h); 4 waves x 16 q rows; KV tile = 32, double-buffered.
// K in LDS: [32][128] rows XOR-swizzled by ((key&7)<<4) on 16B slots.
// V^T in LDS: [128 d][32 key] rows (64B) XOR-swizzled by (((d>>1)&3)<<4).
__global__ __launch_bounds__(256) void attn_kernel(const u16* __restrict__ Q,
                                                   const u16* __restrict__ Kt,
                                                   const u16* __restrict__ VT,
                                                   u16* __restrict__ O) {
  __shared__ u16 Ks[2][32 * 128];
  __shared__ u16 Vs[2][32 * 128];
  __shared__ u16 Ps[4][16 * 32];

  const int bid = blockIdx.x;
  const int qb = 31 - (bid >> 6);        // heavy blocks first
  const int h = bid & 31;
  const int b = (bid >> 5) & 1;
  const int g = h >> 2;
  const int tid = threadIdx.x;
  const int lane = tid & 63;
  const int wv = tid >> 6;
  const int qrow0 = qb * 64 + wv * 16;
  const float scale = 0.08838834764831845f;

  bf16x8 qf[4];
  {
    const int qr = qrow0 + (lane & 15);
    const u16* qptr = Q + (size_t)(b * S_ + qr) * (NH_ * HD_) + h * HD_ + (lane >> 4) * 8;
#pragma unroll
    for (int c = 0; c < 4; c++) qf[c] = *(const bf16x8*)(qptr + c * 32);
  }

  float m[4], l[4];
  f32x4 o[8];
#pragma unroll
  for (int r = 0; r < 4; r++) { m[r] = -1e30f; l[r] = 0.f; }
#pragma unroll
  for (int c = 0; c < 8; c++)
#pragma unroll
    for (int r = 0; r < 4; r++) o[c][r] = 0.f;

  const int nkv = 2 * qb + 2;

  // staging geometry (per wave: 2 K loads + 2 V loads = 4 GLDS per tile)
  const int kkey_ = wv * 4 + (lane >> 4);        // + p*16
  const int kcb_ = (lane & 15) * 16;
  const int vd_ = wv * 16 + (lane >> 2);         // + p*64
  const int vkb_ = (lane & 3) * 16;

  auto STAGE = [&](int t, int buf) {
#pragma unroll
    for (int p = 0; p < 2; p++) {
      int key = p * 16 + kkey_;
      int cbs = kcb_ ^ ((key & 7) << 4);
      const u16* ksrc = Kt + (size_t)(b * S_ + t * 32 + key) * (NKV_ * HD_) + g * HD_ + (cbs >> 1);
      GLDS(ksrc, &Ks[buf][(p * 4 + wv) * 512]);
      int d = p * 64 + vd_;
      int kbs = vkb_ ^ (((d >> 1) & 3) << 4);
      const u16* vsrc = VT + (size_t)(g * HD_ + d) * (B_ * S_) + b * S_ + t * 32 + (kbs >> 1);
      GLDS(vsrc, &Vs[buf][(p * 4 + wv) * 512]);
    }
  };

  STAGE(0, 0);
  int cur = 0;

  for (int t = 0; t < nkv; t++) {
    const bool pf = (t + 1 < nkv);
    if (pf) {
      STAGE(t + 1, cur ^ 1);
      asm volatile("s_waitcnt vmcnt(4)" ::: "memory");
    } else {
      asm volatile("s_waitcnt vmcnt(0)" ::: "memory");
    }
    BAR();
    SCHED0();

    if (t * 32 <= qrow0 + 15) {
      // ---- QK^T ----
      f32x4 s[2];
#pragma unroll
      for (int n = 0; n < 2; n++) {
        f32x4 sc;
#pragma unroll
        for (int r = 0; r < 4; r++) sc[r] = 0.f;
        int kcol = n * 16 + (lane & 15);
#pragma unroll
        for (int c = 0; c < 4; c++) {
          int colb = c * 64 + ((lane >> 4) * 16);
          int addr = kcol * 256 + (colb ^ ((kcol & 7) << 4));
          bf16x8 kf = *(const bf16x8*)((const char*)Ks[cur] + addr);
          sc = __builtin_amdgcn_mfma_f32_16x16x32_bf16(qf[c], kf, sc, 0, 0, 0);
        }
        s[n] = sc;
      }
      // ---- causal mask ----
      if (t * 32 + 31 > qrow0) {
#pragma unroll
        for (int n = 0; n < 2; n++) {
          int k = t * 32 + n * 16 + (lane & 15);
#pragma unroll
          for (int r = 0; r < 4; r++) {
            int q = qrow0 + (lane >> 4) * 4 + r;
            if (k > q) s[n][r] = -1e9f;
          }
        }
      }
      // ---- online softmax ----
      float mx[4];
#pragma unroll
      for (int r = 0; r < 4; r++) mx[r] = fmaxf(s[0][r], s[1][r]);
#pragma unroll
      for (int off = 1; off < 16; off <<= 1)
#pragma unroll
        for (int r = 0; r < 4; r++) mx[r] = fmaxf(mx[r], __shfl_xor(mx[r], off));
      float alpha[4], mn[4];
#pragma unroll
      for (int r = 0; r < 4; r++) {
        mn[r] = fmaxf(m[r], mx[r]);
        alpha[r] = __expf(scale * (m[r] - mn[r]));
        m[r] = mn[r];
      }
      float rs[4];
#pragma unroll
      for (int r = 0; r < 4; r++) {
        s[0][r] = __expf(scale * (s[0][r] - mn[r]));
        s[1][r] = __expf(scale * (s[1][r] - mn[r]));
        rs[r] = s[0][r] + s[1][r];
      }
#pragma unroll
      for (int off = 1; off < 16; off <<= 1)
#pragma unroll
        for (int r = 0; r < 4; r++) rs[r] += __shfl_xor(rs[r], off);
#pragma unroll
      for (int r = 0; r < 4; r++) l[r] = l[r] * alpha[r] + rs[r];
#pragma unroll
      for (int c = 0; c < 8; c++)
#pragma unroll
        for (int r = 0; r < 4; r++) o[c][r] *= alpha[r];
      // ---- P -> A-frag via per-wave LDS bounce ----
#pragma unroll
      for (int n = 0; n < 2; n++)
#pragma unroll
        for (int r = 0; r < 4; r++)
          Ps[wv][((lane >> 4) * 4 + r) * 32 + n * 16 + (lane & 15)] = f2b(s[n][r]);
      asm volatile("s_waitcnt lgkmcnt(0)" ::: "memory");
      bf16x8 pa = *(const bf16x8*)&Ps[wv][(lane & 15) * 32 + (lane >> 4) * 8];
      // ---- PV: vector V^T fragments ----
#pragma unroll
      for (int c = 0; c < 8; c++) {
        int d = c * 16 + (lane & 15);
        int addr = d * 64 + (((lane >> 4) * 16) ^ (((d >> 1) & 3) << 4));
        bf16x8 vf = *(const bf16x8*)((const char*)Vs[cur] + addr);
        o[c] = __builtin_amdgcn_mfma_f32_16x16x32_bf16(pa, vf, o[c], 0, 0, 0);
      }
    }
    asm volatile("s_waitcnt lgkmcnt(0)" ::: "memory");
    SCHED0();
    BAR();
    cur ^= 1;
  }

  // ---- epilogue ----
#pragma unroll
  for (int c = 0; c < 8; c++)
#pragma unroll
    for (int r = 0; r < 4; r++) {
      int q = qrow0 + (lane >> 4) * 4 + r;
      float val = o[c][r] / l[r];
      O[(size_t)(b * S_ + q) * (NH_ * HD_) + h * HD_ + c * 16 + (lane & 15)] = f2b(val);
    }
}

// ---------------- launch ----------------
extern "C" void kernel_launch(void* const* d_in, const int* in_sizes, int n_in,
                              void* d_out, int out_size, void* d_ws, size_t ws_size,
                              hipStream_t stream) {
  const float* x  = (const float*)d_in[0];
  const float* wq = (const float*)d_in[1];
  const float* wk = (const float*)d_in[2];
  const float* wv = (const float*)d_in[3];
  const float* wo = (const float*)d_in[4];
  const float* fc = (const float*)d_in[5];
  const float* fs = (const float*)d_in[6];

  char* ws = (char*)d_ws;
  u16* Xb  = (u16*)(ws);                 // 33.5 MB  (later reused as Ow)
  u16* Wqb = (u16*)(ws + 33554432);      // 33.5 MB  (later reused as Wob)
  u16* Wkb = (u16*)(ws + 67108864);      // 8.4 MB
  u16* Wvb = (u16*)(ws + 75497472);      // 8.4 MB
  u16* Qw  = (u16*)(ws + 83886080);      // 33.5 MB
  u16* Kw  = (u16*)(ws + 117440512);     // 8.4 MB
  u16* Vw  = (u16*)(ws + 125829120);     // 8.4 MB  (V^T layout [1024][4096])
  u16* Ow  = Xb;
  u16* Wob = Wqb;

  auto cvt = [&](const float* in, u16* out, int n) {
    int n4 = n >> 2;
    int blocks = (n4 + 255) / 256; if (blocks > 2048) blocks = 2048;
    cvt_kernel<<<dim3(blocks), dim3(256), 0, stream>>>(in, out, n4);
  };
  cvt(x,  Xb,  B_ * S_ * DIM_);
  cvt(wq, Wqb, DIM_ * DIM_);
  cvt(wk, Wkb, NKV_ * HD_ * DIM_);
  cvt(wv, Wvb, NKV_ * HD_ * DIM_);

  gemm_bt<0><<<dim3(32 * 32), 256, 0, stream>>>(Xb, Wqb, Qw, 4096, 4096, 4096);
  gemm_bt<0><<<dim3(32 * 8),  256, 0, stream>>>(Xb, Wkb, Kw, 4096, 1024, 4096);
  gemm_bt<2><<<dim3(32 * 8),  256, 0, stream>>>(Xb, Wvb, Vw, 4096, 1024, 4096);  // V^T

  cvt(wo, Wob, DIM_ * DIM_);

  rope_kernel<<<dim3((B_ * S_ * NH_ * 64) / 256), 256, 0, stream>>>(Qw, fc, fs, NH_);
  rope_kernel<<<dim3((B_ * S_ * NKV_ * 64) / 256), 256, 0, stream>>>(Kw, fc, fs, NKV_);

  attn_kernel<<<dim3(B_ * NH_ * (S_ / 64)), 256, 0, stream>>>(Qw, Kw, Vw, Ow);

  gemm_bt<1><<<dim3(32 * 32), 256, 0, stream>>>(Ow, Wob, d_out, 4096, 4096, 4096);
}

// Round 3
// 698.534 us; speedup vs baseline: 1.6818x; 1.2121x over previous
//
#include <hip/hip_runtime.h>

typedef unsigned short u16;
typedef unsigned int u32;
typedef __bf16 bf16_t;
typedef bf16_t bf16x8 __attribute__((ext_vector_type(8)));
typedef float f32x4 __attribute__((ext_vector_type(4)));

#define B_ 2
#define S_ 2048
#define DIM_ 4096
#define NH_ 32
#define NKV_ 8
#define HD_ 128

__device__ __forceinline__ u16 f2b(float f) {
  union { float f; unsigned u; } x; x.f = f;
  unsigned r = x.u + 0x7fffu + ((x.u >> 16) & 1u);
  return (u16)(r >> 16);
}
__device__ __forceinline__ float b2f(u16 u) {
  union { unsigned u; float f; } x; x.u = ((unsigned)u) << 16;
  return x.f;
}
__device__ __forceinline__ u32 cvtpk(float lo, float hi) {
  u32 r;
  asm volatile("v_cvt_pk_bf16_f32 %0, %1, %2" : "=v"(r) : "v"(lo), "v"(hi));
  return r;
}

#define GLDS(gsrc, ldst) \
  __builtin_amdgcn_global_load_lds((const __attribute__((address_space(1))) void*)(gsrc), \
                                   (__attribute__((address_space(3))) void*)(ldst), 16, 0, 0)
#define BAR()    __builtin_amdgcn_s_barrier()
#define SCHED0() __builtin_amdgcn_sched_barrier(0)

// ---------------- f32 -> bf16 conversion ----------------
__global__ void cvt_kernel(const float* __restrict__ in, u16* __restrict__ out, int n4) {
  int i = blockIdx.x * blockDim.x + threadIdx.x;
  int stride = gridDim.x * blockDim.x;
  for (; i < n4; i += stride) {
    float4 v = ((const float4*)in)[i];
    ushort4 o;
    o.x = f2b(v.x); o.y = f2b(v.y); o.z = f2b(v.z); o.w = f2b(v.w);
    ((ushort4*)out)[i] = o;
  }
}

// ---------------- RoPE (in-place on bf16) ----------------
__global__ void rope_kernel(u16* __restrict__ t, const float* __restrict__ fc,
                            const float* __restrict__ fs, int nheads) {
  int idx = blockIdx.x * blockDim.x + threadIdx.x;
  int ppr = nheads * 64;
  int row = idx / ppr;
  int pr = idx - row * ppr;
  int h = pr >> 6, j = pr & 63;
  int s = row & (S_ - 1);
  float c = fc[s * 64 + j], sn = fs[s * 64 + j];
  u16* p = t + (size_t)row * (size_t)(nheads * HD_) + h * HD_ + j * 2;
  float tr = b2f(p[0]), ti = b2f(p[1]);
  p[0] = f2b(tr * c - ti * sn);
  p[1] = f2b(tr * sn + ti * c);
}

// ---------------- GEMM: C = A[M,K] * B[N,K]^T ----------------
// MODE 0: bf16 row-major [M][N]; MODE 1: f32 row-major [M][N];
// MODE 2: bf16 col-major [N][M]; MODE 3: dual (col<1024 -> Cout row-major ld=1024;
//         col>=1024 -> Cout2 col-major [col-1024][M], ld=M)
template<int MODE>
__global__ __launch_bounds__(256) void gemm_bt(const u16* __restrict__ A,
                                               const u16* __restrict__ B,
                                               void* __restrict__ Cout,
                                               void* __restrict__ Cout2,
                                               int M, int N, int K) {
  __shared__ u16 As[128 * 32];
  __shared__ u16 Bs[128 * 32];
  const int nbn = N >> 7;
  const int bm = blockIdx.x / nbn;
  const int bn = blockIdx.x - bm * nbn;
  const int tid = threadIdx.x;
  const int lane = tid & 63;
  const int wv = tid >> 6;
  const int wr = wv >> 1, wc = wv & 1;

  f32x4 acc[4][4];
#pragma unroll
  for (int i = 0; i < 4; i++)
#pragma unroll
    for (int j = 0; j < 4; j++)
#pragma unroll
      for (int r = 0; r < 4; r++) acc[i][j][r] = 0.0f;

  const int srow = tid >> 2;
  const int scol = (tid & 3) * 8;
  const u16* Abase = A + (size_t)(bm * 128 + srow) * K + scol;
  const u16* Bbase = B + (size_t)(bn * 128 + srow) * K + scol;

  const int koffr = (lane >> 4) * 8;
  const int mrow = lane & 15;

  for (int k0 = 0; k0 < K; k0 += 32) {
    __syncthreads();
    GLDS(Abase + k0,                    &As[wv * 512]);
    GLDS(Abase + (size_t)64 * K + k0,   &As[(4 + wv) * 512]);
    GLDS(Bbase + k0,                    &Bs[wv * 512]);
    GLDS(Bbase + (size_t)64 * K + k0,   &Bs[(4 + wv) * 512]);
    __syncthreads();
    bf16x8 af[4], bfr[4];
#pragma unroll
    for (int i = 0; i < 4; i++)
      af[i] = *(const bf16x8*)&As[(wr * 64 + i * 16 + mrow) * 32 + koffr];
#pragma unroll
    for (int j = 0; j < 4; j++)
      bfr[j] = *(const bf16x8*)&Bs[(wc * 64 + j * 16 + mrow) * 32 + koffr];
#pragma unroll
    for (int i = 0; i < 4; i++)
#pragma unroll
      for (int j = 0; j < 4; j++)
        acc[i][j] = __builtin_amdgcn_mfma_f32_16x16x32_bf16(af[i], bfr[j], acc[i][j], 0, 0, 0);
  }

  const int r0 = bm * 128 + wr * 64 + (lane >> 4) * 4;
  const int c0 = bn * 128 + wc * 64 + (lane & 15);
#pragma unroll
  for (int i = 0; i < 4; i++)
#pragma unroll
    for (int j = 0; j < 4; j++)
#pragma unroll
      for (int r = 0; r < 4; r++) {
        int row = r0 + i * 16 + r;
        int col = c0 + j * 16;
        float v = acc[i][j][r];
        if (MODE == 1)      ((float*)Cout)[(size_t)row * N + col] = v;
        else if (MODE == 0) ((u16*)Cout)[(size_t)row * N + col]  = f2b(v);
        else if (MODE == 2) ((u16*)Cout)[(size_t)col * M + row]  = f2b(v);
        else {
          if (col < 1024) ((u16*)Cout)[(size_t)row * 1024 + col] = f2b(v);
          else            ((u16*)Cout2)[(size_t)(col - 1024) * M + row] = f2b(v);
        }
      }
}

// ---------------- Flash attention (causal, GQA 4:1) ----------------
// 1 block = 64 q rows of one (b,h); 4 waves x 16 q rows; KV tile = 32, double-buffered.
// Swapped QK^T: s = mfma(K_frag, Q_frag) so each lane holds 8 scores of ONE q-row
// (q = lane&15, keys = n*16 + (lane>>4)*4 + r). Softmax = in-reg reduce + 2 shfl.
__global__ __launch_bounds__(256) void attn_kernel(const u16* __restrict__ Q,
                                                   const u16* __restrict__ Kt,
                                                   const u16* __restrict__ VT,
                                                   u16* __restrict__ O) {
  __shared__ u16 Ks[2][32 * 128];
  __shared__ u16 Vs[2][32 * 128];
  __shared__ u16 Ps[4][16 * 40];   // padded rows: 40 u16 = 80 B (16B-aligned stride)

  const int bid = blockIdx.x;
  const int qb = 31 - (bid >> 6);        // heavy blocks first
  const int h = bid & 31;
  const int b = (bid >> 5) & 1;
  const int g = h >> 2;
  const int tid = threadIdx.x;
  const int lane = tid & 63;
  const int wv = tid >> 6;
  const int qrow0 = qb * 64 + wv * 16;
  const float scale = 0.08838834764831845f;  // 1/sqrt(128)

  // Q fragment (B-operand): col = lane&15 -> q row; k = (lane>>4)*8+j
  bf16x8 qf[4];
  {
    const int qr = qrow0 + (lane & 15);
    const u16* qptr = Q + (size_t)(b * S_ + qr) * (NH_ * HD_) + h * HD_ + (lane >> 4) * 8;
#pragma unroll
    for (int c = 0; c < 4; c++) qf[c] = *(const bf16x8*)(qptr + c * 32);
  }

  float m = -1e30f, l = 0.f;   // per-lane scalars (q = lane&15)
  f32x4 o[8];
#pragma unroll
  for (int c = 0; c < 8; c++)
#pragma unroll
    for (int r = 0; r < 4; r++) o[c][r] = 0.f;

  const int nkv = 2 * qb + 2;

  const int kkey_ = wv * 4 + (lane >> 4);
  const int kcb_ = (lane & 15) * 16;
  const int vd_ = wv * 16 + (lane >> 2);
  const int vkb_ = (lane & 3) * 16;

  auto STAGE = [&](int t, int buf) {
#pragma unroll
    for (int p = 0; p < 2; p++) {
      int key = p * 16 + kkey_;
      int cbs = kcb_ ^ ((key & 7) << 4);
      const u16* ksrc = Kt + (size_t)(b * S_ + t * 32 + key) * (NKV_ * HD_) + g * HD_ + (cbs >> 1);
      GLDS(ksrc, &Ks[buf][(p * 4 + wv) * 512]);
      int d = p * 64 + vd_;
      int kbs = vkb_ ^ (((d >> 1) & 3) << 4);
      const u16* vsrc = VT + (size_t)(g * HD_ + d) * (B_ * S_) + b * S_ + t * 32 + (kbs >> 1);
      GLDS(vsrc, &Vs[buf][(p * 4 + wv) * 512]);
    }
  };

  STAGE(0, 0);
  int cur = 0;

  const int qloc = lane & 15;          // local q row
  const int grp = lane >> 4;           // key group (4 keys per n-frag)
  u16* psrow = &Ps[wv][qloc * 40];

  for (int t = 0; t < nkv; t++) {
    const bool pf = (t + 1 < nkv);
    if (pf) {
      STAGE(t + 1, cur ^ 1);
      asm volatile("s_waitcnt vmcnt(4)" ::: "memory");
    } else {
      asm volatile("s_waitcnt vmcnt(0)" ::: "memory");
    }
    BAR();
    SCHED0();

    if (t * 32 <= qrow0 + 15) {
      // ---- QK^T (swapped): rows of D = keys, cols = q ----
      f32x4 s[2];
      __builtin_amdgcn_s_setprio(1);
#pragma unroll
      for (int n = 0; n < 2; n++) {
        f32x4 sc;
#pragma unroll
        for (int r = 0; r < 4; r++) sc[r] = 0.f;
        int krow = n * 16 + qloc;   // key index inside tile (frag "row" slot = lane&15)
#pragma unroll
        for (int c = 0; c < 4; c++) {
          int colb = c * 64 + (grp * 16);
          int addr = krow * 256 + (colb ^ ((krow & 7) << 4));
          bf16x8 kf = *(const bf16x8*)((const char*)Ks[cur] + addr);
          sc = __builtin_amdgcn_mfma_f32_16x16x32_bf16(kf, qf[c], sc, 0, 0, 0);
        }
        s[n] = sc;
      }
      __builtin_amdgcn_s_setprio(0);
      // Per lane now: q = qrow0+qloc, scores for keys t*32 + n*16 + grp*4 + r
      // ---- causal mask ----
      const int q = qrow0 + qloc;
      if (t * 32 + 31 > qrow0) {
#pragma unroll
        for (int n = 0; n < 2; n++)
#pragma unroll
          for (int r = 0; r < 4; r++) {
            int k = t * 32 + n * 16 + grp * 4 + r;
            if (k > q) s[n][r] = -1e9f;
          }
      }
      // ---- row max: 7 in-reg + 2 shfl ----
      float pmax = fmaxf(fmaxf(fmaxf(s[0][0], s[0][1]), fmaxf(s[0][2], s[0][3])),
                         fmaxf(fmaxf(s[1][0], s[1][1]), fmaxf(s[1][2], s[1][3])));
      pmax = fmaxf(pmax, __shfl_xor(pmax, 16));
      pmax = fmaxf(pmax, __shfl_xor(pmax, 32));
      // ---- defer-max rescale ----
      if (__any(pmax > m + 64.f)) {
        float mn = fmaxf(m, pmax);
        float alpha = __expf(scale * (m - mn));
        m = mn;
        l *= alpha;
        float ar[4];
#pragma unroll
        for (int r = 0; r < 4; r++) ar[r] = __shfl(alpha, grp * 4 + r);
#pragma unroll
        for (int c = 0; c < 8; c++)
#pragma unroll
          for (int r = 0; r < 4; r++) o[c][r] *= ar[r];
      }
      // ---- P = exp(scale*(s - m)) ----
      const float msc = m * scale;
      float p[2][4];
#pragma unroll
      for (int n = 0; n < 2; n++)
#pragma unroll
        for (int r = 0; r < 4; r++)
          p[n][r] = __expf(fmaf(s[n][r], scale, -msc));
      float rs = ((p[0][0] + p[0][1]) + (p[0][2] + p[0][3])) +
                 ((p[1][0] + p[1][1]) + (p[1][2] + p[1][3]));
      rs += __shfl_xor(rs, 16);
      rs += __shfl_xor(rs, 32);
      l += rs;
      // ---- pack P -> Ps (bf16), 2x ds_write_b64 ----
      {
        u32 w[2][2];
#pragma unroll
        for (int n = 0; n < 2; n++) {
          w[n][0] = cvtpk(p[n][0], p[n][1]);
          w[n][1] = cvtpk(p[n][2], p[n][3]);
        }
        *(u32*)&psrow[0 * 16 + grp * 4]     = w[0][0];
        *(u32*)&psrow[0 * 16 + grp * 4 + 2] = w[0][1];
        *(u32*)&psrow[1 * 16 + grp * 4]     = w[1][0];
        *(u32*)&psrow[1 * 16 + grp * 4 + 2] = w[1][1];
      }
      asm volatile("s_waitcnt lgkmcnt(0)" ::: "memory");
      SCHED0();
      // PV A-frag: row = lane&15 = q, k = grp*8 + j
      bf16x8 pa = *(const bf16x8*)&psrow[grp * 8];
      // ---- PV ----
      __builtin_amdgcn_s_setprio(1);
#pragma unroll
      for (int c = 0; c < 8; c++) {
        int d = c * 16 + qloc;
        int addr = d * 64 + ((grp * 16) ^ (((d >> 1) & 3) << 4));
        bf16x8 vf = *(const bf16x8*)((const char*)Vs[cur] + addr);
        o[c] = __builtin_amdgcn_mfma_f32_16x16x32_bf16(pa, vf, o[c], 0, 0, 0);
      }
      __builtin_amdgcn_s_setprio(0);
    }
    asm volatile("s_waitcnt lgkmcnt(0)" ::: "memory");
    SCHED0();
    BAR();
    cur ^= 1;
  }

  // ---- epilogue: O rows = (lane>>4)*4 + r, cols = c*16 + qloc ----
  float lr[4];
#pragma unroll
  for (int r = 0; r < 4; r++) lr[r] = 1.0f / __shfl(l, grp * 4 + r);
#pragma unroll
  for (int c = 0; c < 8; c++)
#pragma unroll
    for (int r = 0; r < 4; r++) {
      int qo = qrow0 + grp * 4 + r;
      float val = o[c][r] * lr[r];
      O[(size_t)(b * S_ + qo) * (NH_ * HD_) + h * HD_ + c * 16 + qloc] = f2b(val);
    }
}

// ---------------- launch ----------------
extern "C" void kernel_launch(void* const* d_in, const int* in_sizes, int n_in,
                              void* d_out, int out_size, void* d_ws, size_t ws_size,
                              hipStream_t stream) {
  const float* x  = (const float*)d_in[0];
  const float* wq = (const float*)d_in[1];
  const float* wk = (const float*)d_in[2];
  const float* wv = (const float*)d_in[3];
  const float* wo = (const float*)d_in[4];
  const float* fc = (const float*)d_in[5];
  const float* fs = (const float*)d_in[6];

  char* ws = (char*)d_ws;
  u16* Xb  = (u16*)(ws);                 // 33.5 MB  (later reused as Ow)
  u16* Wqb = (u16*)(ws + 33554432);      // 33.5 MB  (later reused as Wob)
  u16* Wkv = (u16*)(ws + 67108864);      // 16.8 MB  (K rows 0..1023, V rows 1024..2047)
  u16* Qw  = (u16*)(ws + 83886080);      // 33.5 MB
  u16* Kw  = (u16*)(ws + 117440512);     // 8.4 MB
  u16* Vw  = (u16*)(ws + 125829120);     // 8.4 MB  (V^T layout [1024][4096])
  u16* Ow  = Xb;
  u16* Wob = Wqb;

  auto cvt = [&](const float* in, u16* out, int n) {
    int n4 = n >> 2;
    int blocks = (n4 + 255) / 256; if (blocks > 2048) blocks = 2048;
    cvt_kernel<<<dim3(blocks), dim3(256), 0, stream>>>(in, out, n4);
  };
  cvt(x,  Xb,  B_ * S_ * DIM_);
  cvt(wq, Wqb, DIM_ * DIM_);
  cvt(wk, Wkv, NKV_ * HD_ * DIM_);
  cvt(wv, Wkv + (size_t)1024 * 4096, NKV_ * HD_ * DIM_);

  gemm_bt<0><<<dim3(32 * 32), 256, 0, stream>>>(Xb, Wqb, Qw, nullptr, 4096, 4096, 4096);
  gemm_bt<3><<<dim3(32 * 16), 256, 0, stream>>>(Xb, Wkv, Kw, Vw, 4096, 2048, 4096);

  cvt(wo, Wob, DIM_ * DIM_);

  rope_kernel<<<dim3((B_ * S_ * NH_ * 64) / 256), 256, 0, stream>>>(Qw, fc, fs, NH_);
  rope_kernel<<<dim3((B_ * S_ * NKV_ * 64) / 256), 256, 0, stream>>>(Kw, fc, fs, NKV_);

  attn_kernel<<<dim3(B_ * NH_ * (S_ / 64)), 256, 0, stream>>>(Qw, Kw, Vw, Ow);

  gemm_bt<1><<<dim3(32 * 32), 256, 0, stream>>>(Ow, Wob, d_out, nullptr, 4096, 4096, 4096);
}

// Round 4
// 578.245 us; speedup vs baseline: 2.0317x; 1.2080x over previous
//
#include <hip/hip_runtime.h>

typedef unsigned short u16;
typedef unsigned int u32;
typedef __bf16 bf16_t;
typedef bf16_t bf16x8 __attribute__((ext_vector_type(8)));
typedef float f32x4 __attribute__((ext_vector_type(4)));

#define B_ 2
#define S_ 2048
#define DIM_ 4096
#define NH_ 32
#define NKV_ 8
#define HD_ 128

__device__ __forceinline__ u16 f2b(float f) {
  union { float f; unsigned u; } x; x.f = f;
  unsigned r = x.u + 0x7fffu + ((x.u >> 16) & 1u);
  return (u16)(r >> 16);
}
__device__ __forceinline__ float b2f(u16 u) {
  union { unsigned u; float f; } x; x.u = ((unsigned)u) << 16;
  return x.f;
}
__device__ __forceinline__ u32 cvtpk(float lo, float hi) {
  u32 r;
  asm volatile("v_cvt_pk_bf16_f32 %0, %1, %2" : "=v"(r) : "v"(lo), "v"(hi));
  return r;
}

#define GLDS(gsrc, ldst) \
  __builtin_amdgcn_global_load_lds((const __attribute__((address_space(1))) void*)(gsrc), \
                                   (__attribute__((address_space(3))) void*)(ldst), 16, 0, 0)
#define BAR()    __builtin_amdgcn_s_barrier()
#define SCHED0() __builtin_amdgcn_sched_barrier(0)

// ---------------- f32 -> bf16 conversion ----------------
__global__ void cvt_kernel(const float* __restrict__ in, u16* __restrict__ out, int n4) {
  int i = blockIdx.x * blockDim.x + threadIdx.x;
  int stride = gridDim.x * blockDim.x;
  for (; i < n4; i += stride) {
    float4 v = ((const float4*)in)[i];
    ushort4 o;
    o.x = f2b(v.x); o.y = f2b(v.y); o.z = f2b(v.z); o.w = f2b(v.w);
    ((ushort4*)out)[i] = o;
  }
}

// ---------------- RoPE (in-place on bf16) ----------------
__global__ void rope_kernel(u16* __restrict__ t, const float* __restrict__ fc,
                            const float* __restrict__ fs, int nheads) {
  int idx = blockIdx.x * blockDim.x + threadIdx.x;
  int ppr = nheads * 64;
  int row = idx / ppr;
  int pr = idx - row * ppr;
  int h = pr >> 6, j = pr & 63;
  int s = row & (S_ - 1);
  float c = fc[s * 64 + j], sn = fs[s * 64 + j];
  u16* p = t + (size_t)row * (size_t)(nheads * HD_) + h * HD_ + j * 2;
  float tr = b2f(p[0]), ti = b2f(p[1]);
  p[0] = f2b(tr * c - ti * sn);
  p[1] = f2b(tr * sn + ti * c);
}

// ---------------- 256x256 8-phase GEMM: C = A[M,K] * B[N,K]^T ----------------
// 8 waves (2M x 4N), BK=64, double-buffered LDS with XOR-swizzle, counted vmcnt.
// MODE 0: bf16 [M][N]; MODE 1: f32 [M][N];
// MODE 3: dual (col<1024 -> Cout bf16 ld=1024; col>=1024 -> Cout2 bf16 col-major [col-1024][M])
template<int MODE>
__global__ __launch_bounds__(512, 2) void gemm256(const u16* __restrict__ A,
                                                  const u16* __restrict__ B,
                                                  void* __restrict__ Cout,
                                                  void* __restrict__ Cout2,
                                                  int M, int N, int K) {
  __shared__ u16 As[2][2][128 * 64];   // [buf][half][row*64+col]
  __shared__ u16 Bs[2][2][128 * 64];
  const int nbn = N >> 8;
  const int nwg = gridDim.x;
  int wg = blockIdx.x;
  wg = (wg & 7) * (nwg >> 3) + (wg >> 3);   // XCD swizzle (nwg % 8 == 0)
  const int bm = wg / nbn;
  const int bn = wg - bm * nbn;
  const int tid = threadIdx.x;
  const int lane = tid & 63;
  const int wv = tid >> 6;
  const int wm = wv >> 2, wn = wv & 3;
  const int qloc = lane & 15, grp = lane >> 4;
  const int NT = K >> 6;   // 64-wide K-tiles (even, >= 4)

  f32x4 acc[8][4];
#pragma unroll
  for (int i = 0; i < 8; i++)
#pragma unroll
    for (int j = 0; j < 4; j++)
#pragma unroll
      for (int r = 0; r < 4; r++) acc[i][j][r] = 0.0f;

  // staging: per GLDS, 8 rows x 64 cols; lane -> row lane>>3, swizzled col
  const int srowl = lane >> 3;
  const int scsw = 8 * ((lane & 7) ^ srowl);     // pre-swizzled source col (elems)
  const size_t rowA = (size_t)(bm * 256 + wv * 16 + srowl) * K + scsw;
  const size_t rowB = (size_t)(bn * 256 + wv * 16 + srowl) * K + scsw;

#define STAGE_A(buf, h, tt) { \
    GLDS(A + rowA + (size_t)((h) * 128) * K + (size_t)(tt) * 64, &As[buf][h][wv * 1024]); \
    GLDS(A + rowA + (size_t)((h) * 128 + 8) * K + (size_t)(tt) * 64, &As[buf][h][wv * 1024 + 512]); }
#define STAGE_B(buf, h, tt) { \
    GLDS(B + rowB + (size_t)((h) * 128) * K + (size_t)(tt) * 64, &Bs[buf][h][wv * 1024]); \
    GLDS(B + rowB + (size_t)((h) * 128 + 8) * K + (size_t)(tt) * 64, &Bs[buf][h][wv * 1024 + 512]); }

  // ---- prologue: tile0 (A+B) into buf0, tile1 B into buf1 ----
  STAGE_A(0, 0, 0); STAGE_A(0, 1, 0);
  STAGE_B(0, 0, 0); STAGE_B(0, 1, 0);
  STAGE_B(1, 0, 1); STAGE_B(1, 1, 1);
  asm volatile("s_waitcnt vmcnt(4)" ::: "memory");   // tile0 fully landed
  BAR();

  for (int t = 0; t < NT; t += 2) {
#pragma unroll
    for (int half = 0; half < 2; half++) {           // tile t+half in buf[half]
      bf16x8 bfr[4][2];
#pragma unroll
      for (int qd = 0; qd < 4; qd++) {
        if (qd == 0) {
#pragma unroll
          for (int j = 0; j < 4; j++)
#pragma unroll
            for (int ks = 0; ks < 2; ks++) {
              int rb = (wn & 1) * 64 + j * 16 + qloc;
              bfr[j][ks] = *(const bf16x8*)((const char*)&Bs[half][wn >> 1][0]
                           + rb * 128 + ((ks * 64 + grp * 16) ^ ((rb & 7) << 4)));
            }
        }
        bf16x8 af[2][2];
#pragma unroll
        for (int ii = 0; ii < 2; ii++)
#pragma unroll
          for (int ks = 0; ks < 2; ks++) {
            int rh = qd * 32 + ii * 16 + qloc;
            af[ii][ks] = *(const bf16x8*)((const char*)&As[half][wm][0]
                         + rh * 128 + ((ks * 64 + grp * 16) ^ ((rh & 7) << 4)));
          }
        // ---- stage schedule (each GLDS targets a region past its last reader's barrier) ----
        const int ph = half * 4 + qd;
        if (ph == 0)      { STAGE_A(1, 0, t + 1); }
        else if (ph == 1) { STAGE_A(1, 1, t + 1); }
        else if (ph == 2) { if (t + 2 < NT) STAGE_B(0, 0, t + 2); }
        else if (ph == 3) { if (t + 2 < NT) STAGE_B(0, 1, t + 2); }
        else if (ph == 4) { if (t + 2 < NT) STAGE_A(0, 0, t + 2); }
        else if (ph == 5) { if (t + 2 < NT) STAGE_A(0, 1, t + 2); }
        else if (ph == 6) { if (t + 3 < NT) STAGE_B(1, 0, t + 3); }
        else              { if (t + 3 < NT) STAGE_B(1, 1, t + 3); }
        BAR();
        __builtin_amdgcn_s_setprio(1);
#pragma unroll
        for (int ii = 0; ii < 2; ii++)
#pragma unroll
          for (int ks = 0; ks < 2; ks++)
#pragma unroll
            for (int j = 0; j < 4; j++)
              acc[qd * 2 + ii][j] = __builtin_amdgcn_mfma_f32_16x16x32_bf16(
                  af[ii][ks], bfr[j][ks], acc[qd * 2 + ii][j], 0, 0, 0);
        __builtin_amdgcn_s_setprio(0);
        SCHED0();
        if (qd == 3) {
          // phase 4: need tile t+1 landed; phase 8: need tile t+2 landed.
          if ((half == 0 ? t + 2 : t + 3) < NT)
            asm volatile("s_waitcnt vmcnt(4)" ::: "memory");
          else
            asm volatile("s_waitcnt vmcnt(0)" ::: "memory");
        }
        BAR();
      }
    }
  }
#undef STAGE_A
#undef STAGE_B

  // ---- epilogue ----
  const int r0g = bm * 256 + wm * 128 + grp * 4;
  const int c0g = bn * 256 + wn * 64 + qloc;
#pragma unroll
  for (int i = 0; i < 8; i++)
#pragma unroll
    for (int j = 0; j < 4; j++)
#pragma unroll
      for (int r = 0; r < 4; r++) {
        int row = r0g + i * 16 + r;
        int col = c0g + j * 16;
        float v = acc[i][j][r];
        if (MODE == 1)      ((float*)Cout)[(size_t)row * N + col] = v;
        else if (MODE == 0) ((u16*)Cout)[(size_t)row * N + col]  = f2b(v);
        else {
          if (col < 1024) ((u16*)Cout)[(size_t)row * 1024 + col] = f2b(v);
          else            ((u16*)Cout2)[(size_t)(col - 1024) * M + row] = f2b(v);
        }
      }
}

// ---------------- Flash attention (causal, GQA 4:1) ----------------
__global__ __launch_bounds__(256) void attn_kernel(const u16* __restrict__ Q,
                                                   const u16* __restrict__ Kt,
                                                   const u16* __restrict__ VT,
                                                   u16* __restrict__ O) {
  __shared__ u16 Ks[2][32 * 128];
  __shared__ u16 Vs[2][32 * 128];
  __shared__ u16 Ps[4][16 * 40];

  const int bid = blockIdx.x;
  const int qb = 31 - (bid >> 6);
  const int h = bid & 31;
  const int b = (bid >> 5) & 1;
  const int g = h >> 2;
  const int tid = threadIdx.x;
  const int lane = tid & 63;
  const int wv = tid >> 6;
  const int qrow0 = qb * 64 + wv * 16;
  const float scale = 0.08838834764831845f;

  bf16x8 qf[4];
  {
    const int qr = qrow0 + (lane & 15);
    const u16* qptr = Q + (size_t)(b * S_ + qr) * (NH_ * HD_) + h * HD_ + (lane >> 4) * 8;
#pragma unroll
    for (int c = 0; c < 4; c++) qf[c] = *(const bf16x8*)(qptr + c * 32);
  }

  float m = -1e30f, l = 0.f;
  f32x4 o[8];
#pragma unroll
  for (int c = 0; c < 8; c++)
#pragma unroll
    for (int r = 0; r < 4; r++) o[c][r] = 0.f;

  const int nkv = 2 * qb + 2;

  const int kkey_ = wv * 4 + (lane >> 4);
  const int kcb_ = (lane & 15) * 16;
  const int vd_ = wv * 16 + (lane >> 2);
  const int vkb_ = (lane & 3) * 16;

  auto STAGE = [&](int t, int buf) {
#pragma unroll
    for (int p = 0; p < 2; p++) {
      int key = p * 16 + kkey_;
      int cbs = kcb_ ^ ((key & 7) << 4);
      const u16* ksrc = Kt + (size_t)(b * S_ + t * 32 + key) * (NKV_ * HD_) + g * HD_ + (cbs >> 1);
      GLDS(ksrc, &Ks[buf][(p * 4 + wv) * 512]);
      int d = p * 64 + vd_;
      int kbs = vkb_ ^ (((d >> 1) & 3) << 4);
      const u16* vsrc = VT + (size_t)(g * HD_ + d) * (B_ * S_) + b * S_ + t * 32 + (kbs >> 1);
      GLDS(vsrc, &Vs[buf][(p * 4 + wv) * 512]);
    }
  };

  STAGE(0, 0);
  int cur = 0;

  const int qloc = lane & 15;
  const int grp = lane >> 4;
  u16* psrow = &Ps[wv][qloc * 40];

  for (int t = 0; t < nkv; t++) {
    const bool pf = (t + 1 < nkv);
    if (pf) {
      STAGE(t + 1, cur ^ 1);
      asm volatile("s_waitcnt vmcnt(4)" ::: "memory");
    } else {
      asm volatile("s_waitcnt vmcnt(0)" ::: "memory");
    }
    BAR();
    SCHED0();

    if (t * 32 <= qrow0 + 15) {
      f32x4 s[2];
      __builtin_amdgcn_s_setprio(1);
#pragma unroll
      for (int n = 0; n < 2; n++) {
        f32x4 sc;
#pragma unroll
        for (int r = 0; r < 4; r++) sc[r] = 0.f;
        int krow = n * 16 + qloc;
#pragma unroll
        for (int c = 0; c < 4; c++) {
          int colb = c * 64 + (grp * 16);
          int addr = krow * 256 + (colb ^ ((krow & 7) << 4));
          bf16x8 kf = *(const bf16x8*)((const char*)Ks[cur] + addr);
          sc = __builtin_amdgcn_mfma_f32_16x16x32_bf16(kf, qf[c], sc, 0, 0, 0);
        }
        s[n] = sc;
      }
      __builtin_amdgcn_s_setprio(0);
      const int q = qrow0 + qloc;
      if (t * 32 + 31 > qrow0) {
#pragma unroll
        for (int n = 0; n < 2; n++)
#pragma unroll
          for (int r = 0; r < 4; r++) {
            int k = t * 32 + n * 16 + grp * 4 + r;
            if (k > q) s[n][r] = -1e9f;
          }
      }
      float pmax = fmaxf(fmaxf(fmaxf(s[0][0], s[0][1]), fmaxf(s[0][2], s[0][3])),
                         fmaxf(fmaxf(s[1][0], s[1][1]), fmaxf(s[1][2], s[1][3])));
      pmax = fmaxf(pmax, __shfl_xor(pmax, 16));
      pmax = fmaxf(pmax, __shfl_xor(pmax, 32));
      if (__any(pmax > m + 64.f)) {
        float mn = fmaxf(m, pmax);
        float alpha = __expf(scale * (m - mn));
        m = mn;
        l *= alpha;
        float ar[4];
#pragma unroll
        for (int r = 0; r < 4; r++) ar[r] = __shfl(alpha, grp * 4 + r);
#pragma unroll
        for (int c = 0; c < 8; c++)
#pragma unroll
          for (int r = 0; r < 4; r++) o[c][r] *= ar[r];
      }
      const float msc = m * scale;
      float p[2][4];
#pragma unroll
      for (int n = 0; n < 2; n++)
#pragma unroll
        for (int r = 0; r < 4; r++)
          p[n][r] = __expf(fmaf(s[n][r], scale, -msc));
      float rs = ((p[0][0] + p[0][1]) + (p[0][2] + p[0][3])) +
                 ((p[1][0] + p[1][1]) + (p[1][2] + p[1][3]));
      rs += __shfl_xor(rs, 16);
      rs += __shfl_xor(rs, 32);
      l += rs;
      {
        u32 w[2][2];
#pragma unroll
        for (int n = 0; n < 2; n++) {
          w[n][0] = cvtpk(p[n][0], p[n][1]);
          w[n][1] = cvtpk(p[n][2], p[n][3]);
        }
        *(u32*)&psrow[0 * 16 + grp * 4]     = w[0][0];
        *(u32*)&psrow[0 * 16 + grp * 4 + 2] = w[0][1];
        *(u32*)&psrow[1 * 16 + grp * 4]     = w[1][0];
        *(u32*)&psrow[1 * 16 + grp * 4 + 2] = w[1][1];
      }
      asm volatile("s_waitcnt lgkmcnt(0)" ::: "memory");
      SCHED0();
      bf16x8 pa = *(const bf16x8*)&psrow[grp * 8];
      __builtin_amdgcn_s_setprio(1);
#pragma unroll
      for (int c = 0; c < 8; c++) {
        int d = c * 16 + qloc;
        int addr = d * 64 + ((grp * 16) ^ (((d >> 1) & 3) << 4));
        bf16x8 vf = *(const bf16x8*)((const char*)Vs[cur] + addr);
        o[c] = __builtin_amdgcn_mfma_f32_16x16x32_bf16(pa, vf, o[c], 0, 0, 0);
      }
      __builtin_amdgcn_s_setprio(0);
    }
    asm volatile("s_waitcnt lgkmcnt(0)" ::: "memory");
    SCHED0();
    BAR();
    cur ^= 1;
  }

  float lr[4];
#pragma unroll
  for (int r = 0; r < 4; r++) lr[r] = 1.0f / __shfl(l, grp * 4 + r);
#pragma unroll
  for (int c = 0; c < 8; c++)
#pragma unroll
    for (int r = 0; r < 4; r++) {
      int qo = qrow0 + grp * 4 + r;
      float val = o[c][r] * lr[r];
      O[(size_t)(b * S_ + qo) * (NH_ * HD_) + h * HD_ + c * 16 + qloc] = f2b(val);
    }
}

// ---------------- launch ----------------
extern "C" void kernel_launch(void* const* d_in, const int* in_sizes, int n_in,
                              void* d_out, int out_size, void* d_ws, size_t ws_size,
                              hipStream_t stream) {
  const float* x  = (const float*)d_in[0];
  const float* wq = (const float*)d_in[1];
  const float* wk = (const float*)d_in[2];
  const float* wv = (const float*)d_in[3];
  const float* wo = (const float*)d_in[4];
  const float* fc = (const float*)d_in[5];
  const float* fs = (const float*)d_in[6];

  char* ws = (char*)d_ws;
  u16* Xb  = (u16*)(ws);                 // 33.5 MB  (later reused as Ow)
  u16* Wqb = (u16*)(ws + 33554432);      // 33.5 MB  (later reused as Wob)
  u16* Wkv = (u16*)(ws + 67108864);      // 16.8 MB  (K rows 0..1023, V rows 1024..2047)
  u16* Qw  = (u16*)(ws + 83886080);      // 33.5 MB
  u16* Kw  = (u16*)(ws + 117440512);     // 8.4 MB
  u16* Vw  = (u16*)(ws + 125829120);     // 8.4 MB  (V^T layout [1024][4096])
  u16* Ow  = Xb;
  u16* Wob = Wqb;

  auto cvt = [&](const float* in, u16* out, int n) {
    int n4 = n >> 2;
    int blocks = (n4 + 255) / 256; if (blocks > 2048) blocks = 2048;
    cvt_kernel<<<dim3(blocks), dim3(256), 0, stream>>>(in, out, n4);
  };
  cvt(x,  Xb,  B_ * S_ * DIM_);
  cvt(wq, Wqb, DIM_ * DIM_);
  cvt(wk, Wkv, NKV_ * HD_ * DIM_);
  cvt(wv, Wkv + (size_t)1024 * 4096, NKV_ * HD_ * DIM_);

  gemm256<0><<<dim3(16 * 16), 512, 0, stream>>>(Xb, Wqb, Qw, nullptr, 4096, 4096, 4096);
  gemm256<3><<<dim3(16 * 8),  512, 0, stream>>>(Xb, Wkv, Kw, Vw, 4096, 2048, 4096);

  cvt(wo, Wob, DIM_ * DIM_);

  rope_kernel<<<dim3((B_ * S_ * NH_ * 64) / 256), 256, 0, stream>>>(Qw, fc, fs, NH_);
  rope_kernel<<<dim3((B_ * S_ * NKV_ * 64) / 256), 256, 0, stream>>>(Kw, fc, fs, NKV_);

  attn_kernel<<<dim3(B_ * NH_ * (S_ / 64)), 256, 0, stream>>>(Qw, Kw, Vw, Ow);

  gemm256<1><<<dim3(16 * 16), 512, 0, stream>>>(Ow, Wob, d_out, nullptr, 4096, 4096, 4096);
}

// Round 5
// 566.278 us; speedup vs baseline: 2.0746x; 1.0211x over previous
//
#include <hip/hip_runtime.h>

typedef unsigned short u16;
typedef unsigned int u32;
typedef __bf16 bf16_t;
typedef bf16_t bf16x8 __attribute__((ext_vector_type(8)));
typedef float f32x4 __attribute__((ext_vector_type(4)));

#define B_ 2
#define S_ 2048
#define DIM_ 4096
#define NH_ 32
#define NKV_ 8
#define HD_ 128

__device__ __forceinline__ u16 f2b(float f) {
  union { float f; unsigned u; } x; x.f = f;
  unsigned r = x.u + 0x7fffu + ((x.u >> 16) & 1u);
  return (u16)(r >> 16);
}
__device__ __forceinline__ float b2f(u16 u) {
  union { unsigned u; float f; } x; x.u = ((unsigned)u) << 16;
  return x.f;
}
__device__ __forceinline__ u32 cvtpk(float lo, float hi) {
  u32 r;
  asm volatile("v_cvt_pk_bf16_f32 %0, %1, %2" : "=v"(r) : "v"(lo), "v"(hi));
  return r;
}

#define GLDS(gsrc, ldst) \
  __builtin_amdgcn_global_load_lds((const __attribute__((address_space(1))) void*)(gsrc), \
                                   (__attribute__((address_space(3))) void*)(ldst), 16, 0, 0)
#define BAR()    __builtin_amdgcn_s_barrier()
#define SCHED0() __builtin_amdgcn_sched_barrier(0)

// ---------------- f32 -> bf16 conversion ----------------
__global__ void cvt_kernel(const float* __restrict__ in, u16* __restrict__ out, int n4) {
  int i = blockIdx.x * blockDim.x + threadIdx.x;
  int stride = gridDim.x * blockDim.x;
  for (; i < n4; i += stride) {
    float4 v = ((const float4*)in)[i];
    ushort4 o;
    o.x = f2b(v.x); o.y = f2b(v.y); o.z = f2b(v.z); o.w = f2b(v.w);
    ((ushort4*)out)[i] = o;
  }
}

// ---------------- RoPE (in-place on bf16) — K only now ----------------
__global__ void rope_kernel(u16* __restrict__ t, const float* __restrict__ fc,
                            const float* __restrict__ fs, int nheads) {
  int idx = blockIdx.x * blockDim.x + threadIdx.x;
  int ppr = nheads * 64;
  int row = idx / ppr;
  int pr = idx - row * ppr;
  int h = pr >> 6, j = pr & 63;
  int s = row & (S_ - 1);
  float c = fc[s * 64 + j], sn = fs[s * 64 + j];
  u16* p = t + (size_t)row * (size_t)(nheads * HD_) + h * HD_ + j * 2;
  float tr = b2f(p[0]), ti = b2f(p[1]);
  p[0] = f2b(tr * c - ti * sn);
  p[1] = f2b(tr * sn + ti * c);
}

// ---------------- 256x256 8-phase GEMM: C = A[M,K] * B[N,K]^T ----------------
template<int MODE>
__global__ __launch_bounds__(512, 2) void gemm256(const u16* __restrict__ A,
                                                  const u16* __restrict__ B,
                                                  void* __restrict__ Cout,
                                                  void* __restrict__ Cout2,
                                                  int M, int N, int K) {
  __shared__ u16 As[2][2][128 * 64];
  __shared__ u16 Bs[2][2][128 * 64];
  const int nbn = N >> 8;
  const int nwg = gridDim.x;
  int wg = blockIdx.x;
  wg = (wg & 7) * (nwg >> 3) + (wg >> 3);
  const int bm = wg / nbn;
  const int bn = wg - bm * nbn;
  const int tid = threadIdx.x;
  const int lane = tid & 63;
  const int wv = tid >> 6;
  const int wm = wv >> 2, wn = wv & 3;
  const int qloc = lane & 15, grp = lane >> 4;
  const int NT = K >> 6;

  f32x4 acc[8][4];
#pragma unroll
  for (int i = 0; i < 8; i++)
#pragma unroll
    for (int j = 0; j < 4; j++)
#pragma unroll
      for (int r = 0; r < 4; r++) acc[i][j][r] = 0.0f;

  const int srowl = lane >> 3;
  const int scsw = 8 * ((lane & 7) ^ srowl);
  const size_t rowA = (size_t)(bm * 256 + wv * 16 + srowl) * K + scsw;
  const size_t rowB = (size_t)(bn * 256 + wv * 16 + srowl) * K + scsw;

#define STAGE_A(buf, h, tt) { \
    GLDS(A + rowA + (size_t)((h) * 128) * K + (size_t)(tt) * 64, &As[buf][h][wv * 1024]); \
    GLDS(A + rowA + (size_t)((h) * 128 + 8) * K + (size_t)(tt) * 64, &As[buf][h][wv * 1024 + 512]); }
#define STAGE_B(buf, h, tt) { \
    GLDS(B + rowB + (size_t)((h) * 128) * K + (size_t)(tt) * 64, &Bs[buf][h][wv * 1024]); \
    GLDS(B + rowB + (size_t)((h) * 128 + 8) * K + (size_t)(tt) * 64, &Bs[buf][h][wv * 1024 + 512]); }

  STAGE_A(0, 0, 0); STAGE_A(0, 1, 0);
  STAGE_B(0, 0, 0); STAGE_B(0, 1, 0);
  STAGE_B(1, 0, 1); STAGE_B(1, 1, 1);
  asm volatile("s_waitcnt vmcnt(4)" ::: "memory");
  BAR();

  for (int t = 0; t < NT; t += 2) {
#pragma unroll
    for (int half = 0; half < 2; half++) {
      bf16x8 bfr[4][2];
#pragma unroll
      for (int qd = 0; qd < 4; qd++) {
        if (qd == 0) {
#pragma unroll
          for (int j = 0; j < 4; j++)
#pragma unroll
            for (int ks = 0; ks < 2; ks++) {
              int rb = (wn & 1) * 64 + j * 16 + qloc;
              bfr[j][ks] = *(const bf16x8*)((const char*)&Bs[half][wn >> 1][0]
                           + rb * 128 + ((ks * 64 + grp * 16) ^ ((rb & 7) << 4)));
            }
        }
        bf16x8 af[2][2];
#pragma unroll
        for (int ii = 0; ii < 2; ii++)
#pragma unroll
          for (int ks = 0; ks < 2; ks++) {
            int rh = qd * 32 + ii * 16 + qloc;
            af[ii][ks] = *(const bf16x8*)((const char*)&As[half][wm][0]
                         + rh * 128 + ((ks * 64 + grp * 16) ^ ((rh & 7) << 4)));
          }
        const int ph = half * 4 + qd;
        if (ph == 0)      { STAGE_A(1, 0, t + 1); }
        else if (ph == 1) { STAGE_A(1, 1, t + 1); }
        else if (ph == 2) { if (t + 2 < NT) STAGE_B(0, 0, t + 2); }
        else if (ph == 3) { if (t + 2 < NT) STAGE_B(0, 1, t + 2); }
        else if (ph == 4) { if (t + 2 < NT) STAGE_A(0, 0, t + 2); }
        else if (ph == 5) { if (t + 2 < NT) STAGE_A(0, 1, t + 2); }
        else if (ph == 6) { if (t + 3 < NT) STAGE_B(1, 0, t + 3); }
        else              { if (t + 3 < NT) STAGE_B(1, 1, t + 3); }
        BAR();
        __builtin_amdgcn_s_setprio(1);
#pragma unroll
        for (int ii = 0; ii < 2; ii++)
#pragma unroll
          for (int ks = 0; ks < 2; ks++)
#pragma unroll
            for (int j = 0; j < 4; j++)
              acc[qd * 2 + ii][j] = __builtin_amdgcn_mfma_f32_16x16x32_bf16(
                  af[ii][ks], bfr[j][ks], acc[qd * 2 + ii][j], 0, 0, 0);
        __builtin_amdgcn_s_setprio(0);
        SCHED0();
        if (qd == 3) {
          if ((half == 0 ? t + 2 : t + 3) < NT)
            asm volatile("s_waitcnt vmcnt(4)" ::: "memory");
          else
            asm volatile("s_waitcnt vmcnt(0)" ::: "memory");
        }
        BAR();
      }
    }
  }
#undef STAGE_A
#undef STAGE_B

  const int r0g = bm * 256 + wm * 128 + grp * 4;
  const int c0g = bn * 256 + wn * 64 + qloc;
#pragma unroll
  for (int i = 0; i < 8; i++)
#pragma unroll
    for (int j = 0; j < 4; j++)
#pragma unroll
      for (int r = 0; r < 4; r++) {
        int row = r0g + i * 16 + r;
        int col = c0g + j * 16;
        float v = acc[i][j][r];
        if (MODE == 1)      ((float*)Cout)[(size_t)row * N + col] = v;
        else if (MODE == 0) ((u16*)Cout)[(size_t)row * N + col]  = f2b(v);
        else {
          if (col < 1024) ((u16*)Cout)[(size_t)row * 1024 + col] = f2b(v);
          else            ((u16*)Cout2)[(size_t)(col - 1024) * M + row] = f2b(v);
        }
      }
}

// ---------------- Flash attention (causal, GQA 4:1) ----------------
// Block = 128 q rows of one (b,h); 4 waves x 32 q (2 q-frags each); KV tile = 32, dbuf.
// Swapped QK^T; Q-RoPE fused at fragment load. K-frag & V-frag reads shared across q-frags.
__global__ __launch_bounds__(256) void attn_kernel(const u16* __restrict__ Q,
                                                   const u16* __restrict__ Kt,
                                                   const u16* __restrict__ VT,
                                                   u16* __restrict__ O,
                                                   const float* __restrict__ fc,
                                                   const float* __restrict__ fs) {
  __shared__ u16 Ks[2][32 * 128];
  __shared__ u16 Vs[2][32 * 128];
  __shared__ u16 Ps[4][32 * 40];   // 32 rows (2 q-frags), stride 80 B

  const int bid = blockIdx.x;
  const int qb = 15 - (bid >> 6);        // heavy blocks first
  const int h = bid & 31;
  const int b = (bid >> 5) & 1;
  const int g = h >> 2;
  const int tid = threadIdx.x;
  const int lane = tid & 63;
  const int wv = tid >> 6;
  const int qrow0 = qb * 128 + wv * 32;
  const float scale = 0.08838834764831845f;

  const int qloc = lane & 15;
  const int grp = lane >> 4;

  // ---- Q fragments with fused RoPE ----
  bf16x8 qf[2][4];
#pragma unroll
  for (int f = 0; f < 2; f++) {
    const int qr = qrow0 + f * 16 + qloc;
    const u16* qptr = Q + (size_t)(b * S_ + qr) * (NH_ * HD_) + h * HD_ + grp * 8;
#pragma unroll
    for (int c = 0; c < 4; c++) {
      union { bf16x8 v; u16 u[8]; } raw;
      raw.v = *(const bf16x8*)(qptr + c * 32);
      const int p0 = c * 16 + grp * 4;
      const float4 cv = *(const float4*)&fc[(size_t)qr * 64 + p0];
      const float4 sv = *(const float4*)&fs[(size_t)qr * 64 + p0];
      union { bf16x8 v; u32 w[4]; } out;
      const float cc[4] = {cv.x, cv.y, cv.z, cv.w};
      const float ss[4] = {sv.x, sv.y, sv.z, sv.w};
#pragma unroll
      for (int j = 0; j < 4; j++) {
        float tr = b2f(raw.u[2 * j]), ti = b2f(raw.u[2 * j + 1]);
        out.w[j] = cvtpk(tr * cc[j] - ti * ss[j], tr * ss[j] + ti * cc[j]);
      }
      qf[f][c] = out.v;
    }
  }

  float m[2] = {-1e30f, -1e30f}, l[2] = {0.f, 0.f};
  f32x4 o[2][8];
#pragma unroll
  for (int f = 0; f < 2; f++)
#pragma unroll
    for (int c = 0; c < 8; c++)
#pragma unroll
      for (int r = 0; r < 4; r++) o[f][c][r] = 0.f;

  const int nkv = 4 * qb + 4;

  const int kkey_ = wv * 4 + grp;
  const int kcb_ = qloc * 16;
  const int vd_ = wv * 16 + (lane >> 2);
  const int vkb_ = (lane & 3) * 16;

  auto STAGE = [&](int t, int buf) {
#pragma unroll
    for (int p = 0; p < 2; p++) {
      int key = p * 16 + kkey_;
      int cbs = kcb_ ^ ((key & 7) << 4);
      const u16* ksrc = Kt + (size_t)(b * S_ + t * 32 + key) * (NKV_ * HD_) + g * HD_ + (cbs >> 1);
      GLDS(ksrc, &Ks[buf][(p * 4 + wv) * 512]);
      int d = p * 64 + vd_;
      int kbs = vkb_ ^ (((d >> 1) & 3) << 4);
      const u16* vsrc = VT + (size_t)(g * HD_ + d) * (B_ * S_) + b * S_ + t * 32 + (kbs >> 1);
      GLDS(vsrc, &Vs[buf][(p * 4 + wv) * 512]);
    }
  };

  STAGE(0, 0);
  int cur = 0;

  u16* psbase = &Ps[wv][0];

  for (int t = 0; t < nkv; t++) {
    const bool pf = (t + 1 < nkv);
    if (pf) {
      STAGE(t + 1, cur ^ 1);
      asm volatile("s_waitcnt vmcnt(4)" ::: "memory");
    } else {
      asm volatile("s_waitcnt vmcnt(0)" ::: "memory");
    }
    BAR();
    SCHED0();

    if (t * 32 <= qrow0 + 31) {
      // ---- QK^T (swapped, K-frags shared across 2 q-frags) ----
      f32x4 s[2][2];
#pragma unroll
      for (int f = 0; f < 2; f++)
#pragma unroll
        for (int n = 0; n < 2; n++)
#pragma unroll
          for (int r = 0; r < 4; r++) s[f][n][r] = 0.f;
      __builtin_amdgcn_s_setprio(1);
#pragma unroll
      for (int n = 0; n < 2; n++) {
        int krow = n * 16 + qloc;
#pragma unroll
        for (int c = 0; c < 4; c++) {
          int colb = c * 64 + (grp * 16);
          int addr = krow * 256 + (colb ^ ((krow & 7) << 4));
          bf16x8 kf = *(const bf16x8*)((const char*)Ks[cur] + addr);
          s[0][n] = __builtin_amdgcn_mfma_f32_16x16x32_bf16(kf, qf[0][c], s[0][n], 0, 0, 0);
          s[1][n] = __builtin_amdgcn_mfma_f32_16x16x32_bf16(kf, qf[1][c], s[1][n], 0, 0, 0);
        }
      }
      __builtin_amdgcn_s_setprio(0);
      // lane holds: s[f][n][r] for q = qrow0 + f*16 + qloc, key = t*32 + n*16 + grp*4 + r
      // ---- causal mask ----
      if (t * 32 + 31 > qrow0) {
#pragma unroll
        for (int f = 0; f < 2; f++) {
          const int q = qrow0 + f * 16 + qloc;
#pragma unroll
          for (int n = 0; n < 2; n++)
#pragma unroll
            for (int r = 0; r < 4; r++) {
              int k = t * 32 + n * 16 + grp * 4 + r;
              if (k > q) s[f][n][r] = -1e9f;
            }
        }
      }
      // ---- row max ----
      float pmax[2];
#pragma unroll
      for (int f = 0; f < 2; f++) {
        pmax[f] = fmaxf(fmaxf(fmaxf(s[f][0][0], s[f][0][1]), fmaxf(s[f][0][2], s[f][0][3])),
                        fmaxf(fmaxf(s[f][1][0], s[f][1][1]), fmaxf(s[f][1][2], s[f][1][3])));
        pmax[f] = fmaxf(pmax[f], __shfl_xor(pmax[f], 16));
        pmax[f] = fmaxf(pmax[f], __shfl_xor(pmax[f], 32));
      }
      // ---- defer-max rescale ----
      bool need = (pmax[0] > m[0] + 64.f) || (pmax[1] > m[1] + 64.f);
      if (__any(need)) {
#pragma unroll
        for (int f = 0; f < 2; f++) {
          float mn = fmaxf(m[f], pmax[f]);
          float alpha = __expf(scale * (m[f] - mn));
          m[f] = mn;
          l[f] *= alpha;
          float ar[4];
#pragma unroll
          for (int r = 0; r < 4; r++) ar[r] = __shfl(alpha, grp * 4 + r);
#pragma unroll
          for (int c = 0; c < 8; c++)
#pragma unroll
            for (int r = 0; r < 4; r++) o[f][c][r] *= ar[r];
        }
      }
      // ---- P = exp(scale*(s-m)), row sums, pack to Ps ----
#pragma unroll
      for (int f = 0; f < 2; f++) {
        const float msc = m[f] * scale;
        float p[2][4];
#pragma unroll
        for (int n = 0; n < 2; n++)
#pragma unroll
          for (int r = 0; r < 4; r++)
            p[n][r] = __expf(fmaf(s[f][n][r], scale, -msc));
        float rs = ((p[0][0] + p[0][1]) + (p[0][2] + p[0][3])) +
                   ((p[1][0] + p[1][1]) + (p[1][2] + p[1][3]));
        rs += __shfl_xor(rs, 16);
        rs += __shfl_xor(rs, 32);
        l[f] += rs;
        u16* psrow = psbase + (f * 16 + qloc) * 40;
        *(u32*)&psrow[0 * 16 + grp * 4]     = cvtpk(p[0][0], p[0][1]);
        *(u32*)&psrow[0 * 16 + grp * 4 + 2] = cvtpk(p[0][2], p[0][3]);
        *(u32*)&psrow[1 * 16 + grp * 4]     = cvtpk(p[1][0], p[1][1]);
        *(u32*)&psrow[1 * 16 + grp * 4 + 2] = cvtpk(p[1][2], p[1][3]);
      }
      asm volatile("s_waitcnt lgkmcnt(0)" ::: "memory");
      SCHED0();
      bf16x8 pa[2];
      pa[0] = *(const bf16x8*)&psbase[(0 * 16 + qloc) * 40 + grp * 8];
      pa[1] = *(const bf16x8*)&psbase[(1 * 16 + qloc) * 40 + grp * 8];
      // ---- PV (V-frags shared across 2 q-frags) ----
      __builtin_amdgcn_s_setprio(1);
#pragma unroll
      for (int c = 0; c < 8; c++) {
        int d = c * 16 + qloc;
        int addr = d * 64 + ((grp * 16) ^ (((d >> 1) & 3) << 4));
        bf16x8 vf = *(const bf16x8*)((const char*)Vs[cur] + addr);
        o[0][c] = __builtin_amdgcn_mfma_f32_16x16x32_bf16(pa[0], vf, o[0][c], 0, 0, 0);
        o[1][c] = __builtin_amdgcn_mfma_f32_16x16x32_bf16(pa[1], vf, o[1][c], 0, 0, 0);
      }
      __builtin_amdgcn_s_setprio(0);
    }
    asm volatile("s_waitcnt lgkmcnt(0)" ::: "memory");
    SCHED0();
    BAR();
    cur ^= 1;
  }

  // ---- epilogue ----
#pragma unroll
  for (int f = 0; f < 2; f++) {
    float lr[4];
#pragma unroll
    for (int r = 0; r < 4; r++) lr[r] = 1.0f / __shfl(l[f], grp * 4 + r);
#pragma unroll
    for (int c = 0; c < 8; c++)
#pragma unroll
      for (int r = 0; r < 4; r++) {
        int qo = qrow0 + f * 16 + grp * 4 + r;
        float val = o[f][c][r] * lr[r];
        O[(size_t)(b * S_ + qo) * (NH_ * HD_) + h * HD_ + c * 16 + qloc] = f2b(val);
      }
  }
}

// ---------------- launch ----------------
extern "C" void kernel_launch(void* const* d_in, const int* in_sizes, int n_in,
                              void* d_out, int out_size, void* d_ws, size_t ws_size,
                              hipStream_t stream) {
  const float* x  = (const float*)d_in[0];
  const float* wq = (const float*)d_in[1];
  const float* wk = (const float*)d_in[2];
  const float* wv = (const float*)d_in[3];
  const float* wo = (const float*)d_in[4];
  const float* fc = (const float*)d_in[5];
  const float* fs = (const float*)d_in[6];

  char* ws = (char*)d_ws;
  u16* Xb  = (u16*)(ws);                 // 33.5 MB  (later reused as Ow)
  u16* Wqb = (u16*)(ws + 33554432);      // 33.5 MB  (later reused as Wob)
  u16* Wkv = (u16*)(ws + 67108864);      // 16.8 MB
  u16* Qw  = (u16*)(ws + 83886080);      // 33.5 MB
  u16* Kw  = (u16*)(ws + 117440512);     // 8.4 MB
  u16* Vw  = (u16*)(ws + 125829120);     // 8.4 MB  (V^T layout [1024][4096])
  u16* Ow  = Xb;
  u16* Wob = Wqb;

  auto cvt = [&](const float* in, u16* out, int n) {
    int n4 = n >> 2;
    int blocks = (n4 + 255) / 256; if (blocks > 2048) blocks = 2048;
    cvt_kernel<<<dim3(blocks), dim3(256), 0, stream>>>(in, out, n4);
  };
  cvt(x,  Xb,  B_ * S_ * DIM_);
  cvt(wq, Wqb, DIM_ * DIM_);
  cvt(wk, Wkv, NKV_ * HD_ * DIM_);
  cvt(wv, Wkv + (size_t)1024 * 4096, NKV_ * HD_ * DIM_);

  gemm256<0><<<dim3(16 * 16), 512, 0, stream>>>(Xb, Wqb, Qw, nullptr, 4096, 4096, 4096);
  gemm256<3><<<dim3(16 * 8),  512, 0, stream>>>(Xb, Wkv, Kw, Vw, 4096, 2048, 4096);

  cvt(wo, Wob, DIM_ * DIM_);

  rope_kernel<<<dim3((B_ * S_ * NKV_ * 64) / 256), 256, 0, stream>>>(Kw, fc, fs, NKV_);

  attn_kernel<<<dim3(B_ * NH_ * (S_ / 128)), 256, 0, stream>>>(Qw, Kw, Vw, Ow, fc, fs);

  gemm256<1><<<dim3(16 * 16), 512, 0, stream>>>(Ow, Wob, d_out, nullptr, 4096, 4096, 4096);
}